// Round 11
// baseline (305.509 us; speedup 1.0000x reference)
//
#include <hip/hip_runtime.h>

#define NN 50000
#define NN0 30000
#define NN1 20000
#define NE 600000
#define INC 128
#define HIDC 128
#define OUTC 40
#define Y1S 2304     // Y1 row stride bytes (1152 bf16: 8 rel slices + root)
#define Y2S 864      // Y2 row stride bytes (432 bf16: 9 slices of 48)
#define XS  256      // X/h row stride bytes (128 bf16)
#define CAP 64
#define OVCAP 65536
#define XB 3125      // xbuild blocks (NN*16/256)
#define FB 2344      // fill blocks
#define P1T 20480    // pack1 threads: 10 chunks * 4 ks * 8 jf * 64
#define P2T 7680     // pack2 threads: 10 chunks * 4 ks * 3 jf * 64

typedef __attribute__((ext_vector_type(4))) float f32x4;
typedef __attribute__((ext_vector_type(8))) short s16x8;

static __device__ __forceinline__ unsigned short f2bf(float f){
  unsigned u = __builtin_bit_cast(unsigned, f);
  u = u + 0x7fffu + ((u >> 16) & 1u);
  return (unsigned short)(u >> 16);
}
static __device__ __forceinline__ float bflo(unsigned w){
  return __builtin_bit_cast(float, w << 16);
}
static __device__ __forceinline__ float bfhi(unsigned w){
  return __builtin_bit_cast(float, w & 0xffff0000u);
}
static __device__ __forceinline__ void gll16(const void* g, void* l){
  __builtin_amdgcn_global_load_lds(
    (const __attribute__((address_space(1))) unsigned int*)g,
    (__attribute__((address_space(3))) unsigned int*)l, 16, 0, 0);
}

// fused grid: [0,XB) gather input features -> X (bf16);
//             [XB,XB+FB) bucket edges; rest: pack B1/B2 (bf16, MFMA layout).
__global__ void build_k(const float* __restrict__ x0, const float* __restrict__ e1,
                        const int* __restrict__ ntp, const int* __restrict__ lix,
                        char* __restrict__ Xb,
                        const int* __restrict__ ei, const int* __restrict__ et,
                        int* __restrict__ deg, int* __restrict__ eb,
                        int* __restrict__ ovf, int* __restrict__ ovc,
                        const float* __restrict__ rw1, const float* __restrict__ qw1,
                        const float* __restrict__ rw2, const float* __restrict__ qw2,
                        short* __restrict__ Bp1, short* __restrict__ Bp2){
  int b = blockIdx.x;
  if(b < XB){
    int tid = b * 256 + threadIdx.x;   // NN*16
    int n = tid >> 4, q = tid & 15;
    if(n >= NN) return;
    int t = ntp[n], li = lix[n];
    const float* s;
    if(t == 0){ li = li < 0 ? 0 : (li > NN0 - 1 ? NN0 - 1 : li); s = x0 + (size_t)li * INC; }
    else      { li = li < 0 ? 0 : (li > NN1 - 1 ? NN1 - 1 : li); s = e1 + (size_t)li * INC; }
    float4 a = ((const float4*)s)[q * 2];
    float4 c = ((const float4*)s)[q * 2 + 1];
    uint4 o;
    o.x = (unsigned)f2bf(a.x) | ((unsigned)f2bf(a.y) << 16);
    o.y = (unsigned)f2bf(a.z) | ((unsigned)f2bf(a.w) << 16);
    o.z = (unsigned)f2bf(c.x) | ((unsigned)f2bf(c.y) << 16);
    o.w = (unsigned)f2bf(c.z) | ((unsigned)f2bf(c.w) << 16);
    *(uint4*)(Xb + (size_t)n * XS + q * 16) = o;
    return;
  }
  if(b < XB + FB){
    int e = (b - XB) * 256 + threadIdx.x;
    if(e >= NE) return;
    int s = ei[e], d = ei[NE + e], t = et[e];
    int pos = atomicAdd(&deg[d], 1);
    if(pos < CAP) eb[d * CAP + pos] = s | (t << 16);
    else { int oi = atomicAdd(ovc, 1); if(oi < OVCAP) ovf[oi] = e; }
    return;
  }
  int tid = (b - XB - FB) * 256 + threadIdx.x;
  if(tid < P1T){
    // B1: chunk nc<8 = rel_w1[nc]; nc=8/9 = root_w1[0/1]. slot=((ks*8+jf)*64+l)
    int l = tid & 63, jf = (tid >> 6) & 7, ks = (tid >> 9) & 3, nc = tid >> 11;
    int cc = jf * 16 + (l & 15);
    int k0 = ks * 32 + (l >> 4) * 8;
    const float* src = (nc < 8) ? (rw1 + ((size_t)nc * HIDC + cc) * INC + k0)
                                : (qw1 + ((size_t)(nc - 8) * HIDC + cc) * INC + k0);
    s16x8 ov;
    #pragma unroll
    for(int jj = 0; jj < 8; jj++) ov[jj] = (short)f2bf(src[jj]);
    ((s16x8*)Bp1)[tid] = ov;
    return;
  }
  int tid2 = tid - P1T;
  if(tid2 >= P2T) return;
  int l = tid2 & 63;
  int q = tid2 >> 6;
  int jf = q % 3; q /= 3;
  int ks = q & 3, nc = q >> 2;
  int cc = jf * 16 + (l & 15);      // <48; cols >=40 zero-padded
  int k0 = ks * 32 + (l >> 4) * 8;
  s16x8 ov;
  #pragma unroll
  for(int jj = 0; jj < 8; jj++){
    float wv = 0.f;
    if(cc < OUTC){
      if(nc < 8) wv = rw2[((size_t)nc * OUTC + cc) * INC + k0 + jj];
      else       wv = qw2[((size_t)(nc - 8) * OUTC + cc) * INC + k0 + jj];
    }
    ov[jj] = (short)f2bf(wv);
  }
  ((s16x8*)Bp2)[tid2] = ov;
}

// T1: Y1[n, nc*128+cc] = (W_nc x_n), nc<8 rel, nc=8 root (per node type).
__global__ __launch_bounds__(512) void t1_k(char* __restrict__ Y, const char* __restrict__ X,
                                            const char* __restrict__ Bp, int nb0){
  __shared__ char lds[65536];
  int b = blockIdx.x;
  int v, rowbase, rowlim;
  if(b < nb0){ v = 0; rowbase = b * 128; rowlim = NN0; }
  else       { v = 1; rowbase = NN0 + (b - nb0) * 128; rowlim = NN; }
  int t = threadIdx.x, w = t >> 6, l = t & 63;
  int rg = w >> 1, cg = w & 1, lm = l & 15, lk = l >> 4;
  int swz = (lm & 7) << 4;

  #pragma unroll
  for(int i = 0; i < 4; i++){
    int s = t + i * 512;
    int row = s >> 4;
    int boff = (s & 15) * 16;
    int srow = rowbase + row; if(srow > NN - 1) srow = NN - 1;
    gll16(X + (size_t)srow * XS + (boff ^ ((row & 7) << 4)), lds + s * 16);
  }
  #pragma unroll
  for(int i = 0; i < 4; i++){ int s = t + i * 512; gll16(Bp + s * 16, lds + 32768 + s * 16); }
  __syncthreads();

  for(int nc = 0; nc < 9; nc++){
    f32x4 acc[2][4];
    #pragma unroll
    for(int rf = 0; rf < 2; rf++)
      #pragma unroll
      for(int cf = 0; cf < 4; cf++) acc[rf][cf] = (f32x4)(0.f);
    #pragma unroll
    for(int ks = 0; ks < 4; ks++){
      int kb = ks * 64 + lk * 16;
      int r0 = rg * 32 + lm;
      s16x8 a0 = *(const s16x8*)(lds + r0 * 256 + (kb ^ swz));
      s16x8 a1 = *(const s16x8*)(lds + (r0 + 16) * 256 + (kb ^ swz));
      #pragma unroll
      for(int cf = 0; cf < 4; cf++){
        s16x8 bj = *(const s16x8*)(lds + 32768 + ((ks * 8 + cg * 4 + cf) * 64 + l) * 16);
        acc[0][cf] = __builtin_amdgcn_mfma_f32_16x16x32_bf16(a0, bj, acc[0][cf], 0, 0, 0);
        acc[1][cf] = __builtin_amdgcn_mfma_f32_16x16x32_bf16(a1, bj, acc[1][cf], 0, 0, 0);
      }
    }
    __syncthreads();
    if(nc < 8){
      int bnc = (nc + 1 == 8) ? (8 + v) : (nc + 1);
      const char* bs = Bp + (size_t)bnc * 32768;
      #pragma unroll
      for(int i = 0; i < 4; i++){ int s = t + i * 512; gll16(bs + s * 16, lds + 32768 + s * 16); }
    }
    #pragma unroll
    for(int cf = 0; cf < 4; cf++){
      int gcol = nc * 128 + cg * 64 + cf * 16 + lm;
      #pragma unroll
      for(int rf = 0; rf < 2; rf++){
        #pragma unroll
        for(int r = 0; r < 4; r++){
          int row = rowbase + rg * 32 + rf * 16 + lk * 4 + r;
          if(row < rowlim)
            *(unsigned short*)(Y + (size_t)row * Y1S + gcol * 2) = f2bf(acc[rf][cf][r]);
        }
      }
    }
    __syncthreads();
  }
}

// T2: Y2[n, nc*48+cc] = (W2_nc h_n). 9 chunks of 48 cols, K=128.
__global__ __launch_bounds__(512) void t2_k(char* __restrict__ Y, const char* __restrict__ X,
                                            const char* __restrict__ Bp, int nb0){
  __shared__ char lds[45056];
  int b = blockIdx.x;
  int v, rowbase, rowlim;
  if(b < nb0){ v = 0; rowbase = b * 128; rowlim = NN0; }
  else       { v = 1; rowbase = NN0 + (b - nb0) * 128; rowlim = NN; }
  int t = threadIdx.x, w = t >> 6, l = t & 63;
  int lm = l & 15, lk = l >> 4;
  int swz = (lm & 7) << 4;

  #pragma unroll
  for(int i = 0; i < 4; i++){
    int s = t + i * 512;
    int row = s >> 4;
    int boff = (s & 15) * 16;
    int srow = rowbase + row; if(srow > NN - 1) srow = NN - 1;
    gll16(X + (size_t)srow * XS + (boff ^ ((row & 7) << 4)), lds + s * 16);
  }
  gll16(Bp + t * 16, lds + 32768 + t * 16);
  if(t < 256) gll16(Bp + (512 + t) * 16, lds + 32768 + (512 + t) * 16);
  __syncthreads();

  for(int nc = 0; nc < 9; nc++){
    f32x4 acc[3];
    #pragma unroll
    for(int j = 0; j < 3; j++) acc[j] = (f32x4)(0.f);
    #pragma unroll
    for(int ks = 0; ks < 4; ks++){
      int kb = ks * 64 + lk * 16;
      int row = w * 16 + lm;
      s16x8 af = *(const s16x8*)(lds + row * 256 + (kb ^ swz));
      #pragma unroll
      for(int jf = 0; jf < 3; jf++){
        s16x8 bj = *(const s16x8*)(lds + 32768 + ((ks * 3 + jf) * 64 + l) * 16);
        acc[jf] = __builtin_amdgcn_mfma_f32_16x16x32_bf16(af, bj, acc[jf], 0, 0, 0);
      }
    }
    __syncthreads();
    if(nc < 8){
      int bnc = (nc + 1 == 8) ? (8 + v) : (nc + 1);
      const char* bs = Bp + (size_t)bnc * 12288;
      gll16(bs + t * 16, lds + 32768 + t * 16);
      if(t < 256) gll16(bs + (512 + t) * 16, lds + 32768 + (512 + t) * 16);
    }
    #pragma unroll
    for(int jf = 0; jf < 3; jf++){
      int gcol = nc * 48 + jf * 16 + lm;
      #pragma unroll
      for(int r = 0; r < 4; r++){
        int row = rowbase + w * 16 + lk * 4 + r;
        if(row < rowlim)
          *(unsigned short*)(Y + (size_t)row * Y2S + gcol * 2) = f2bf(acc[jf][r]);
      }
    }
    __syncthreads();
  }
}

// agg1: one wave per dst. Bucket entries are wave-uniform -> readfirstlane so
// address math + type switch are SCALAR; per-edge VALU = 2 FMA.
__global__ __launch_bounds__(256) void agg1_k(const int* __restrict__ eb, const int* __restrict__ deg,
                                              const char* __restrict__ Y, char* __restrict__ Xh,
                                              const float* __restrict__ qb1,
                                              const int* __restrict__ ovf, const int* __restrict__ ovc,
                                              const int* __restrict__ ei, const int* __restrict__ et){
  int wid = (blockIdx.x * 256 + threadIdx.x) >> 6;
  int l = threadIdx.x & 63;
  if(wid >= NN) return;
  int d = __builtin_amdgcn_readfirstlane(wid);
  int v = d >= NN0 ? 1 : 0;
  int dg = deg[d];
  int nb = dg < CAP ? dg : CAP;
  int voff = l * 4;
  float acc[16];
  #pragma unroll
  for(int j = 0; j < 16; j++) acc[j] = 0.f;
  int c0 = 0, c1 = 0, c2 = 0, c3 = 0, c4 = 0, c5 = 0, c6 = 0, c7 = 0;

#define ACCUM(T, W) { \
  float fx_ = bflo(W), fy_ = bfhi(W); \
  switch(T){ \
    case 0: acc[0]  += fx_; acc[1]  += fy_; c0++; break; \
    case 1: acc[2]  += fx_; acc[3]  += fy_; c1++; break; \
    case 2: acc[4]  += fx_; acc[5]  += fy_; c2++; break; \
    case 3: acc[6]  += fx_; acc[7]  += fy_; c3++; break; \
    case 4: acc[8]  += fx_; acc[9]  += fy_; c4++; break; \
    case 5: acc[10] += fx_; acc[11] += fy_; c5++; break; \
    case 6: acc[12] += fx_; acc[13] += fy_; c6++; break; \
    default: acc[14] += fx_; acc[15] += fy_; c7++; break; \
  } }
#define EADDR(P) (Y + (size_t)((P) & 0xffff) * Y1S + ((((P) >> 16)) << 8) + voff)

  int base = d * CAP;
  int i = 0;
  for(; i + 3 < nb; i += 4){
    int p0 = __builtin_amdgcn_readfirstlane(eb[base + i + 0]);
    int p1 = __builtin_amdgcn_readfirstlane(eb[base + i + 1]);
    int p2 = __builtin_amdgcn_readfirstlane(eb[base + i + 2]);
    int p3 = __builtin_amdgcn_readfirstlane(eb[base + i + 3]);
    unsigned w0 = *(const unsigned*)EADDR(p0);
    unsigned w1 = *(const unsigned*)EADDR(p1);
    unsigned w2 = *(const unsigned*)EADDR(p2);
    unsigned w3 = *(const unsigned*)EADDR(p3);
    ACCUM(p0 >> 16, w0);
    ACCUM(p1 >> 16, w1);
    ACCUM(p2 >> 16, w2);
    ACCUM(p3 >> 16, w3);
  }
  for(; i < nb; i++){
    int p0 = __builtin_amdgcn_readfirstlane(eb[base + i]);
    unsigned w0 = *(const unsigned*)EADDR(p0);
    ACCUM(p0 >> 16, w0);
  }
  if(dg > CAP){
    int oc = *ovc; if(oc > OVCAP) oc = OVCAP;
    for(int k = 0; k < oc; k++){
      int e = __builtin_amdgcn_readfirstlane(ovf[k]);
      if(ei[NE + e] != d) continue;
      int s = __builtin_amdgcn_readfirstlane(ei[e]);
      int t0 = __builtin_amdgcn_readfirstlane(et[e]);
      unsigned w0 = *(const unsigned*)(Y + (size_t)s * Y1S + t0 * 256 + voff);
      ACCUM(t0, w0);
    }
  }
#undef EADDR
#undef ACCUM

  float hx = 0.f, hy = 0.f;
#define FOLD(TT, CT) { float iv = 1.0f / (float)((CT) > 1 ? (CT) : 1); \
    hx = fmaf(acc[2*(TT)], iv, hx); hy = fmaf(acc[2*(TT)+1], iv, hy); }
  FOLD(0, c0); FOLD(1, c1); FOLD(2, c2); FOLD(3, c3);
  FOLD(4, c4); FOLD(5, c5); FOLD(6, c6); FOLD(7, c7);
#undef FOLD
  unsigned rw = *(const unsigned*)(Y + (size_t)d * Y1S + 2048 + voff);
  hx += bflo(rw); hy += bfhi(rw);
  float2 bb = *(const float2*)(qb1 + v * HIDC + 2 * l);
  hx += bb.x; hy += bb.y;
  hx = hx > 0.f ? hx : 0.f;
  hy = hy > 0.f ? hy : 0.f;
  unsigned o = (unsigned)f2bf(hx) | ((unsigned)f2bf(hy) << 16);
  *(unsigned*)(Xh + (size_t)d * XS + voff) = o;
}

// agg2: one wave per dst (24 active lanes for loads). Scalar entry dispatch.
// Final bias + log_softmax -> out.
__global__ __launch_bounds__(256) void agg2_k(const int* __restrict__ eb, const int* __restrict__ deg,
                                              const char* __restrict__ Y,
                                              const float* __restrict__ qb2, float* __restrict__ outp,
                                              const int* __restrict__ ovf, const int* __restrict__ ovc,
                                              const int* __restrict__ ei, const int* __restrict__ et){
  int wid = (blockIdx.x * 256 + threadIdx.x) >> 6;
  int l = threadIdx.x & 63;
  if(wid >= NN) return;
  int d = __builtin_amdgcn_readfirstlane(wid);
  int v = d >= NN0 ? 1 : 0;
  int dg = deg[d];
  int nb = dg < CAP ? dg : CAP;
  int act = l < 24;
  int voff = l * 4;
  float acc[16];
  #pragma unroll
  for(int j = 0; j < 16; j++) acc[j] = 0.f;
  int c0 = 0, c1 = 0, c2 = 0, c3 = 0, c4 = 0, c5 = 0, c6 = 0, c7 = 0;

#define ACCUM(T, W) { \
  float fx_ = bflo(W), fy_ = bfhi(W); \
  switch(T){ \
    case 0: acc[0]  += fx_; acc[1]  += fy_; c0++; break; \
    case 1: acc[2]  += fx_; acc[3]  += fy_; c1++; break; \
    case 2: acc[4]  += fx_; acc[5]  += fy_; c2++; break; \
    case 3: acc[6]  += fx_; acc[7]  += fy_; c3++; break; \
    case 4: acc[8]  += fx_; acc[9]  += fy_; c4++; break; \
    case 5: acc[10] += fx_; acc[11] += fy_; c5++; break; \
    case 6: acc[12] += fx_; acc[13] += fy_; c6++; break; \
    default: acc[14] += fx_; acc[15] += fy_; c7++; break; \
  } }
#define ELOAD(P, W) { W = 0; if(act) W = *(const unsigned*)(Y + (size_t)((P) & 0xffff) * Y2S + ((P) >> 16) * 96 + voff); }

  int base = d * CAP;
  int i = 0;
  for(; i + 3 < nb; i += 4){
    int p0 = __builtin_amdgcn_readfirstlane(eb[base + i + 0]);
    int p1 = __builtin_amdgcn_readfirstlane(eb[base + i + 1]);
    int p2 = __builtin_amdgcn_readfirstlane(eb[base + i + 2]);
    int p3 = __builtin_amdgcn_readfirstlane(eb[base + i + 3]);
    unsigned w0, w1, w2, w3;
    ELOAD(p0, w0); ELOAD(p1, w1); ELOAD(p2, w2); ELOAD(p3, w3);
    ACCUM(p0 >> 16, w0);
    ACCUM(p1 >> 16, w1);
    ACCUM(p2 >> 16, w2);
    ACCUM(p3 >> 16, w3);
  }
  for(; i < nb; i++){
    int p0 = __builtin_amdgcn_readfirstlane(eb[base + i]);
    unsigned w0; ELOAD(p0, w0);
    ACCUM(p0 >> 16, w0);
  }
  if(dg > CAP){
    int oc = *ovc; if(oc > OVCAP) oc = OVCAP;
    for(int k = 0; k < oc; k++){
      int e = __builtin_amdgcn_readfirstlane(ovf[k]);
      if(ei[NE + e] != d) continue;
      int s = __builtin_amdgcn_readfirstlane(ei[e]);
      int t0 = __builtin_amdgcn_readfirstlane(et[e]);
      unsigned w0 = 0;
      if(act) w0 = *(const unsigned*)(Y + (size_t)s * Y2S + t0 * 96 + voff);
      ACCUM(t0, w0);
    }
  }
#undef ELOAD
#undef ACCUM

  float vx = 0.f, vy = 0.f;
#define FOLD(TT, CT) { float iv = 1.0f / (float)((CT) > 1 ? (CT) : 1); \
    vx = fmaf(acc[2*(TT)], iv, vx); vy = fmaf(acc[2*(TT)+1], iv, vy); }
  FOLD(0, c0); FOLD(1, c1); FOLD(2, c2); FOLD(3, c3);
  FOLD(4, c4); FOLD(5, c5); FOLD(6, c6); FOLD(7, c7);
#undef FOLD
  if(act){
    unsigned rw = *(const unsigned*)(Y + (size_t)d * Y2S + 768 + voff);
    vx += bflo(rw); vy += bfhi(rw);
  }
  if(l < 20){
    float2 bb = *(const float2*)(qb2 + v * OUTC + 2 * l);
    vx += bb.x; vy += bb.y;
  }
  float mm = (l < 20) ? fmaxf(vx, vy) : -1e30f;
  #pragma unroll
  for(int s = 1; s < 64; s <<= 1) mm = fmaxf(mm, __shfl_xor(mm, s, 64));
  float ex = (l < 20) ? (__expf(vx - mm) + __expf(vy - mm)) : 0.f;
  #pragma unroll
  for(int s = 1; s < 64; s <<= 1) ex += __shfl_xor(ex, s, 64);
  float ls = logf(ex);
  if(l < 20){
    float2 o; o.x = vx - mm - ls; o.y = vy - mm - ls;
    *(float2*)(outp + (size_t)d * OUTC + 2 * l) = o;
  }
}

extern "C" void kernel_launch(void* const* d_in, const int* in_sizes, int n_in,
                              void* d_out, int out_size, void* d_ws, size_t ws_size,
                              hipStream_t stream){
  const float* x0  = (const float*)d_in[0];
  const float* e1  = (const float*)d_in[1];
  const float* rw1 = (const float*)d_in[2];
  const float* qw1 = (const float*)d_in[3];
  const float* qb1 = (const float*)d_in[4];
  const float* rw2 = (const float*)d_in[5];
  const float* qw2 = (const float*)d_in[6];
  const float* qb2 = (const float*)d_in[7];
  const int*   ei  = (const int*)d_in[8];
  const int*   et  = (const int*)d_in[9];
  const int*   ntp = (const int*)d_in[10];
  const int*   lix = (const int*)d_in[11];
  float* out = (float*)d_out;

  const size_t Y_OFF   = 0;             // 50000*2304 = 115,200,000
  const size_t X_OFF   = 115200000;     // 50000*256  = 12,800,000
  const size_t EB_OFF  = 128000000;     // 12,800,000
  const size_t DEG_OFF = 140800000;     // 200,000
  const size_t OVC_OFF = 141000000;     // 256
  const size_t OVF_OFF = 141000256;     // 262,144
  const size_t BP1_OFF = 141262400;     // 10*32768 = 327,680
  const size_t BP2_OFF = 141590080;     // 10*12288 = 122,880
  const size_t TOTAL   = 141712960;
  if(ws_size < TOTAL) return;

  char* ws = (char*)d_ws;
  char*  Y   = ws + Y_OFF;
  char*  X   = ws + X_OFF;
  int*   eb  = (int*)(ws + EB_OFF);
  int*   deg = (int*)(ws + DEG_OFF);
  int*   ovc = (int*)(ws + OVC_OFF);
  int*   ovf = (int*)(ws + OVF_OFF);
  short* Bp1 = (short*)(ws + BP1_OFF);
  short* Bp2 = (short*)(ws + BP2_OFF);

  int nb0 = (NN0 + 127) / 128;                  // 235
  int nb1 = (NN - NN0 + 127) / 128;             // 157
  int p1b = P1T / 256;                          // 80
  int p2b = P2T / 256;                          // 30

  hipMemsetAsync(deg, 0, 200000 + 256, stream);           // deg + ovc (adjacent)
  build_k<<<XB + FB + p1b + p2b, 256, 0, stream>>>(x0, e1, ntp, lix, X, ei, et, deg, eb, ovf, ovc,
                                                   rw1, qw1, rw2, qw2, Bp1, Bp2);
  t1_k<<<nb0 + nb1, 512, 0, stream>>>(Y, X, (const char*)Bp1, nb0);
  agg1_k<<<(NN + 3) / 4, 256, 0, stream>>>(eb, deg, Y, X, qb1, ovf, ovc, ei, et);
  t2_k<<<nb0 + nb1, 512, 0, stream>>>(Y, X, (const char*)Bp2, nb0);
  agg2_k<<<(NN + 3) / 4, 256, 0, stream>>>(eb, deg, Y, qb2, out, ovf, ovc, ei, et);
}